// Round 2
// baseline (406.660 us; speedup 1.0000x reference)
//
#include <hip/hip_runtime.h>

#define M_DIM 8192   // BATCH * SEQ
#define IN_F  4096
#define RANK_ 1024
#define OUT_F 4096

typedef __bf16 bf16x8 __attribute__((ext_vector_type(8)));
typedef float  f32x4  __attribute__((ext_vector_type(4)));
typedef unsigned short ushort8 __attribute__((ext_vector_type(8)));

__device__ __forceinline__ unsigned short f2bf(float f) {
    unsigned int u = __float_as_uint(f);
    u += 0x7FFFu + ((u >> 16) & 1u);   // round-to-nearest-even
    return (unsigned short)(u >> 16);
}

// ---- fp32 -> bf16 bulk convert (vectorized: 8 elems/thread/iter) ----
__global__ void cvt_f32_bf16(const float* __restrict__ in,
                             unsigned short* __restrict__ out, int n8) {
    int stride = gridDim.x * blockDim.x;
    for (int i = blockIdx.x * blockDim.x + threadIdx.x; i < n8; i += stride) {
        const float4* p = (const float4*)in + (size_t)i * 2;
        float4 a = p[0];
        float4 b = p[1];
        ushort8 o;
        o[0] = f2bf(a.x); o[1] = f2bf(a.y); o[2] = f2bf(a.z); o[3] = f2bf(a.w);
        o[4] = f2bf(b.x); o[5] = f2bf(b.y); o[6] = f2bf(b.z); o[7] = f2bf(b.w);
        ((ushort8*)out)[i] = o;
    }
}

// ---- Vt [IN][RANK] f32 -> VtT [RANK][IN] bf16, scaled by S[r] ----
__global__ void transpose_scale(const float* __restrict__ vt,
                                const float* __restrict__ S,
                                unsigned short* __restrict__ out) {
    __shared__ float tile[32][33];
    const int kb = blockIdx.x * 32;          // over IN
    const int rb = blockIdx.y * 32;          // over RANK
    const int tx = threadIdx.x & 31;
    const int ty = threadIdx.x >> 5;         // 0..7
    #pragma unroll
    for (int j = 0; j < 32; j += 8)
        tile[ty + j][tx] = vt[(size_t)(kb + ty + j) * RANK_ + rb + tx];
    __syncthreads();
    #pragma unroll
    for (int j = 0; j < 32; j += 8) {
        int r = rb + ty + j;
        float s = S[r];
        out[(size_t)r * IN_F + kb + tx] = f2bf(tile[tx][ty + j] * s);
    }
}

// ---- bf16 GEMM, C[M][N] = A[M][K] @ B^T where B is [N][K] (row-major, K contiguous)
// 128x128 tile, BK=64, 4 waves (2x2), each wave 64x64 = 4x4 fragments of 16x16x32.
// LDS XOR-swizzle (16B chunk col ^= row&7) applied via pre-swizzled global source
// (global_load_lds writes linearly) + swizzled ds_read address.
// EPI==0: store bf16.  EPI==1: add bias, store f32.
template<int EPI>
__global__ __launch_bounds__(256, 2)
void gemm_bt(const unsigned short* __restrict__ A,
             const unsigned short* __restrict__ B,
             void* __restrict__ Cv,
             const float* __restrict__ bias,
             int N, int K) {
    __shared__ unsigned short sA[128 * 64];
    __shared__ unsigned short sB[128 * 64];

    const int l  = threadIdx.x & 63;
    const int w  = threadIdx.x >> 6;
    const int wr = w >> 1, wc = w & 1;
    const int col0 = blockIdx.x * 128;
    const int row0 = blockIdx.y * 128;

    const unsigned short* gA = A + (size_t)row0 * K;
    const unsigned short* gB = B + (size_t)col0 * K;

    f32x4 acc[4][4];
    const f32x4 z = {0.f, 0.f, 0.f, 0.f};
    #pragma unroll
    for (int i = 0; i < 4; ++i)
        #pragma unroll
        for (int j = 0; j < 4; ++j) acc[i][j] = z;

    // stage one 128x64 bf16 tile (16 KB): 4 global_load_lds x 4 waves x 64 lanes x 16B
    auto stage = [&](const unsigned short* __restrict__ g,
                     unsigned short* __restrict__ s, int k0) {
        #pragma unroll
        for (int i = 0; i < 4; ++i) {
            int chunk = (i * 4 + w) * 64 + l;      // 0..1023, 16B chunks
            int r  = chunk >> 3;                   // tile row 0..127
            int c  = chunk & 7;                    // chunk col 0..7
            int cs = c ^ (r & 7);                  // inverse-swizzled source col
            const unsigned short* src = g + (size_t)r * K + k0 + cs * 8;
            __builtin_amdgcn_global_load_lds(
                (const __attribute__((address_space(1))) void*)src,
                (__attribute__((address_space(3))) void*)(s + chunk * 8),
                16, 0, 0);
        }
    };

    stage(gA, sA, 0);
    stage(gB, sB, 0);

    const int nK = K >> 6;
    for (int kt = 0; kt < nK; ++kt) {
        __syncthreads();   // compiler drains vmcnt(0): staged tile visible
        #pragma unroll
        for (int kk = 0; kk < 2; ++kk) {
            bf16x8 av[4], bv[4];
            #pragma unroll
            for (int mi = 0; mi < 4; ++mi) {
                int r = wr * 64 + mi * 16 + (l & 15);
                int c = (kk * 4 + (l >> 4)) ^ (r & 7);
                av[mi] = *(const bf16x8*)((const char*)sA + r * 128 + c * 16);
            }
            #pragma unroll
            for (int nj = 0; nj < 4; ++nj) {
                int r = wc * 64 + nj * 16 + (l & 15);
                int c = (kk * 4 + (l >> 4)) ^ (r & 7);
                bv[nj] = *(const bf16x8*)((const char*)sB + r * 128 + c * 16);
            }
            #pragma unroll
            for (int mi = 0; mi < 4; ++mi)
                #pragma unroll
                for (int nj = 0; nj < 4; ++nj)
                    acc[mi][nj] = __builtin_amdgcn_mfma_f32_16x16x32_bf16(
                        av[mi], bv[nj], acc[mi][nj], 0, 0, 0);
        }
        if (kt + 1 < nK) {
            __syncthreads();   // all waves done reading before restage
            stage(gA, sA, (kt + 1) << 6);
            stage(gB, sB, (kt + 1) << 6);
        }
    }

    // epilogue: C/D layout col = lane&15, row = (lane>>4)*4 + reg  [m89]
    const int cr = (l >> 4) << 2;
    const int cc = l & 15;
    const int mB = row0 + wr * 64;
    const int nB = col0 + wc * 64;
    if (EPI == 0) {
        unsigned short* C = (unsigned short*)Cv;
        #pragma unroll
        for (int mi = 0; mi < 4; ++mi)
            #pragma unroll
            for (int nj = 0; nj < 4; ++nj) {
                size_t base = (size_t)(mB + mi * 16 + cr) * N + (nB + nj * 16 + cc);
                #pragma unroll
                for (int r = 0; r < 4; ++r)
                    C[base + (size_t)r * N] = f2bf(acc[mi][nj][r]);
            }
    } else {
        float* C = (float*)Cv;
        #pragma unroll
        for (int nj = 0; nj < 4; ++nj) {
            float bvv = bias[nB + nj * 16 + cc];
            #pragma unroll
            for (int mi = 0; mi < 4; ++mi) {
                size_t base = (size_t)(mB + mi * 16 + cr) * N + (nB + nj * 16 + cc);
                #pragma unroll
                for (int r = 0; r < 4; ++r)
                    C[base + (size_t)r * N] = acc[mi][nj][r] + bvv;
            }
        }
    }
}

extern "C" void kernel_launch(void* const* d_in, const int* in_sizes, int n_in,
                              void* d_out, int out_size, void* d_ws, size_t ws_size,
                              hipStream_t stream) {
    const float* x    = (const float*)d_in[0];
    const float* U    = (const float*)d_in[1];
    const float* S    = (const float*)d_in[2];
    const float* Vt   = (const float*)d_in[3];
    const float* bias = (const float*)d_in[4];

    // workspace layout (total 96 MB)
    unsigned short* xb  = (unsigned short*)d_ws;                 // [8192][4096] bf16, 64 MB
    unsigned short* vtT = xb  + (size_t)M_DIM * IN_F;            // [1024][4096] bf16,  8 MB
    unsigned short* ub  = vtT + (size_t)RANK_ * IN_F;            // [4096][1024] bf16,  8 MB
    unsigned short* h   = ub  + (size_t)OUT_F * RANK_;           // [8192][1024] bf16, 16 MB

    hipLaunchKernelGGL(cvt_f32_bf16, dim3(2048), dim3(256), 0, stream,
                       x, xb, (M_DIM * IN_F) / 8);
    hipLaunchKernelGGL(cvt_f32_bf16, dim3(512), dim3(256), 0, stream,
                       U, ub, (OUT_F * RANK_) / 8);
    hipLaunchKernelGGL(transpose_scale, dim3(IN_F / 32, RANK_ / 32), dim3(256), 0, stream,
                       Vt, S, vtT);

    // GEMM1: h[8192][1024] = xb @ vtT^T   (K = 4096), store bf16
    hipLaunchKernelGGL((gemm_bt<0>), dim3(RANK_ / 128, M_DIM / 128), dim3(256), 0, stream,
                       xb, vtT, (void*)h, (const float*)nullptr, RANK_, IN_F);
    // GEMM2: y[8192][4096] = h @ ub^T + bias   (K = 1024), store f32
    hipLaunchKernelGGL((gemm_bt<1>), dim3(OUT_F / 128, M_DIM / 128), dim3(256), 0, stream,
                       h, ub, d_out, bias, OUT_F, RANK_);
}